// Round 1
// baseline (162.242 us; speedup 1.0000x reference)
//
#include <hip/hip_runtime.h>
#include <hip/hip_bf16.h>

// RecurrentCrossLinearAttention: N=16, S=4096, H=16, D=64, M=64, fp32.
// One workgroup per (n,h) pair (256 wgs = 1/CU), 512 threads = 8 waves.
// Waves split S; each thread accumulates an 8x8 (m,d) tile in registers.
// Register-double-buffered global->LDS staging; end-of-kernel LDS merge.

#define S_LEN  4096
#define NHEAD  16
#define DDIM   64
#define MDIM   64
#define CHUNK  64
#define NCHUNK (S_LEN / CHUNK)
#define NTH    512

#define OUT_SOFF  16384                   // N*H*M
#define OUT_ZOFF  (16384 + 1048576)       // + N*H*M*D

__device__ __forceinline__ float elup1(float x) {
    // elu(x) + 1 = x+1 (x>0) else exp(x)
    return x > 0.0f ? x + 1.0f : __expf(x);
}

__global__ __launch_bounds__(NTH, 2)
void rcla_kernel(const float* __restrict__ query,
                 const float* __restrict__ keys,
                 const float* __restrict__ values,
                 const float* __restrict__ kmask,
                 float* __restrict__ out)
{
    __shared__ float Ks[CHUNK * DDIM];    // 16 KB staging (elu'd, masked K)
    __shared__ float Vs[CHUNK * MDIM];    // 16 KB staging (raw V)
    __shared__ float buf[MDIM * DDIM];    // 16 KB merge buffer (S_state tile)
    __shared__ float zbuf[DDIM];
    __shared__ float qbuf[DDIM];

    const int t    = threadIdx.x;
    const int pair = blockIdx.x;          // n*16 + h
    const int nIdx = pair >> 4;
    const int hIdx = pair & 15;
    const int wave = t >> 6;
    const int lane = t & 63;
    const int mgrp = lane >> 3;           // 0..7 -> m0
    const int dgrp = lane & 7;            // 0..7 -> d0
    const int m0 = mgrp * 8;
    const int d0 = dgrp * 8;

    // staging map: thread t loads float4s at (row=t>>4, col=(t&15)*4) and row+32
    const int srow0 = t >> 4;             // 0..31
    const int srow1 = srow0 + 32;
    const int scol  = (t & 15) * 4;

    const size_t rowStride = (size_t)NHEAD * DDIM;   // 1024 floats
    const size_t base = ((size_t)nIdx * S_LEN * NHEAD + hIdx) * DDIM;
    const float* kp0 = keys   + base + (size_t)srow0 * rowStride + scol;
    const float* kp1 = keys   + base + (size_t)srow1 * rowStride + scol;
    const float* vp0 = values + base + (size_t)srow0 * rowStride + scol;
    const float* vp1 = values + base + (size_t)srow1 * rowStride + scol;
    const float* mp  = kmask + (size_t)nIdx * S_LEN + srow0;

    float acc[8][8];
    float zz[8];
#pragma unroll
    for (int i = 0; i < 8; ++i) {
        zz[i] = 0.0f;
#pragma unroll
        for (int j = 0; j < 8; ++j) acc[i][j] = 0.0f;
    }

    // prologue: issue chunk-0 loads
    float4 ka = *(const float4*)kp0;
    float4 kb = *(const float4*)kp1;
    float4 va = *(const float4*)vp0;
    float4 vb = *(const float4*)vp1;
    float mk0 = mp[0], mk1 = mp[32];

    const int rbase = wave * 8;
    const size_t step = (size_t)CHUNK * rowStride;

    for (int c = 0; c < NCHUNK; ++c) {
        // transform K in registers (waits on the in-flight loads)
        float4 k0, k1;
        k0.x = elup1(ka.x) * mk0;  k0.y = elup1(ka.y) * mk0;
        k0.z = elup1(ka.z) * mk0;  k0.w = elup1(ka.w) * mk0;
        k1.x = elup1(kb.x) * mk1;  k1.y = elup1(kb.y) * mk1;
        k1.z = elup1(kb.z) * mk1;  k1.w = elup1(kb.w) * mk1;
        float4 v0 = va, v1 = vb;

        __syncthreads();   // all waves done reading LDS for chunk c-1
        *(float4*)&Ks[srow0 * DDIM + scol] = k0;
        *(float4*)&Ks[srow1 * DDIM + scol] = k1;
        *(float4*)&Vs[srow0 * MDIM + scol] = v0;
        *(float4*)&Vs[srow1 * MDIM + scol] = v1;
        __syncthreads();   // chunk c staged

        if (c + 1 < NCHUNK) {  // issue chunk c+1 loads; latency hides under compute
            kp0 += step; kp1 += step; vp0 += step; vp1 += step; mp += CHUNK;
            ka = *(const float4*)kp0;
            kb = *(const float4*)kp1;
            va = *(const float4*)vp0;
            vb = *(const float4*)vp1;
            mk0 = mp[0]; mk1 = mp[32];
        }

        // compute: this wave's 8 rows of the chunk
#pragma unroll
        for (int r = 0; r < 8; ++r) {
            const int row = rbase + r;
            const float4 kk0 = *(const float4*)&Ks[row * DDIM + d0];
            const float4 kk1 = *(const float4*)&Ks[row * DDIM + d0 + 4];
            const float4 vv0 = *(const float4*)&Vs[row * MDIM + m0];
            const float4 vv1 = *(const float4*)&Vs[row * MDIM + m0 + 4];
            const float kv[8] = {kk0.x, kk0.y, kk0.z, kk0.w, kk1.x, kk1.y, kk1.z, kk1.w};
            const float vm[8] = {vv0.x, vv0.y, vv0.z, vv0.w, vv1.x, vv1.y, vv1.z, vv1.w};
#pragma unroll
            for (int mi = 0; mi < 8; ++mi)
#pragma unroll
                for (int di = 0; di < 8; ++di)
                    acc[mi][di] = fmaf(vm[mi], kv[di], acc[mi][di]);
#pragma unroll
            for (int di = 0; di < 8; ++di) zz[di] += kv[di];
        }
    }

    // Q row into LDS (covered by the merge-loop barriers)
    if (t < DDIM) qbuf[t] = elup1(query[(size_t)pair * DDIM + t]);

    // sequential cross-wave merge of acc tiles (and z) through LDS
    for (int w = 0; w < 8; ++w) {
        if (wave == w) {
#pragma unroll
            for (int mi = 0; mi < 8; ++mi) {
                float4* row = (float4*)&buf[(m0 + mi) * DDIM + d0];
                if (w == 0) {
                    row[0] = make_float4(acc[mi][0], acc[mi][1], acc[mi][2], acc[mi][3]);
                    row[1] = make_float4(acc[mi][4], acc[mi][5], acc[mi][6], acc[mi][7]);
                } else {
                    float4 a = row[0], b = row[1];
                    a.x += acc[mi][0]; a.y += acc[mi][1]; a.z += acc[mi][2]; a.w += acc[mi][3];
                    b.x += acc[mi][4]; b.y += acc[mi][5]; b.z += acc[mi][6]; b.w += acc[mi][7];
                    row[0] = a; row[1] = b;
                }
            }
            if (mgrp == 0) {
#pragma unroll
                for (int i = 0; i < 8; ++i) {
                    if (w == 0) zbuf[d0 + i] = zz[i];
                    else        zbuf[d0 + i] += zz[i];
                }
            }
        }
        __syncthreads();
    }

    // write S_state: each thread 8 contiguous floats
    {
        const int row = t >> 3;           // m
        const int col = (t & 7) * 8;      // d
        float* dst = out + OUT_SOFF + ((size_t)pair * MDIM + row) * DDIM + col;
        *(float4*)dst       = *(float4*)&buf[row * DDIM + col];
        *((float4*)dst + 1) = *(float4*)&buf[row * DDIM + col + 4];
    }

    // write Z
    if (t < DDIM) out[OUT_ZOFF + (size_t)pair * DDIM + t] = zbuf[t];

    // V_out: wave 0, lane = m
    if (wave == 0) {
        float q  = qbuf[lane];
        float zp = q * zbuf[lane];
#pragma unroll
        for (int off = 32; off >= 1; off >>= 1) zp += __shfl_xor(zp, off, 64);
        const float qz = 1.0f / (zp + 1e-6f);
        float vs = 0.0f;
#pragma unroll
        for (int d = 0; d < DDIM; d += 4) {
            const float4 sv = *(const float4*)&buf[lane * DDIM + d];
            vs = fmaf(qbuf[d],     sv.x, vs);
            vs = fmaf(qbuf[d + 1], sv.y, vs);
            vs = fmaf(qbuf[d + 2], sv.z, vs);
            vs = fmaf(qbuf[d + 3], sv.w, vs);
        }
        out[(size_t)pair * MDIM + lane] = qz * vs;
    }
}

extern "C" void kernel_launch(void* const* d_in, const int* in_sizes, int n_in,
                              void* d_out, int out_size, void* d_ws, size_t ws_size,
                              hipStream_t stream) {
    const float* q  = (const float*)d_in[0];
    const float* k  = (const float*)d_in[1];
    const float* v  = (const float*)d_in[2];
    const float* km = (const float*)d_in[3];
    float* out = (float*)d_out;
    rcla_kernel<<<dim3(256), dim3(NTH), 0, stream>>>(q, k, v, km, out);
}